// Round 9
// baseline (2443.512 us; speedup 1.0000x reference)
//
#include <hip/hip_runtime.h>
#include <hip/hip_fp16.h>
#include <math.h>

#define EPSBN 1e-5f
#define NBMAX 2048          // max buckets (256 rows each)
#define TPT 32              // entries per thread in passA
#define CAPS 8192           // sortK LDS staging capacity (entries)

typedef int int4v __attribute__((ext_vector_type(4)));

__device__ __forceinline__ float elu1(float x) { return x > 0.f ? x : expm1f(x); }

// dot of 8 half pairs (packed in float4 bit patterns), fp32 accumulate
__device__ __forceinline__ float dot8h(float4 hv, float4 wv, float acc) {
#if defined(__has_builtin)
#if __has_builtin(__builtin_amdgcn_fdot2)
    typedef _Float16 h2v __attribute__((ext_vector_type(2)));
    union { float4 f; h2v h[4]; } a, b;
    a.f = hv; b.f = wv;
#pragma unroll
    for (int i = 0; i < 4; ++i)
        acc = __builtin_amdgcn_fdot2(a.h[i], b.h[i], acc, false);
    return acc;
#endif
#endif
    const __half2* ha = (const __half2*)&hv;
    const __half2* wa = (const __half2*)&wv;
#pragma unroll
    for (int i = 0; i < 4; ++i) {
        float2 hf = __half22float2(ha[i]);
        float2 wf = __half22float2(wa[i]);
        acc = fmaf(hf.x, wf.x, acc);
        acc = fmaf(hf.y, wf.y, acc);
    }
    return acc;
}

// ============================================================================
// Bucket histogram (1563 counters, L2-resident) + tiny scan
// ============================================================================

__global__ void bhist(const int* __restrict__ out_idx, int* __restrict__ bcnt, int M) {
    int m = (blockIdx.x * blockDim.x + threadIdx.x) * 4;
    if (m >= M) return;
    size_t e = (size_t)blockIdx.y * M + m;
    if (m + 3 < M) {
        int4v v = __builtin_nontemporal_load((const int4v*)(out_idx + e));
        atomicAdd(&bcnt[v.x >> 8], 1);
        atomicAdd(&bcnt[v.y >> 8], 1);
        atomicAdd(&bcnt[v.z >> 8], 1);
        atomicAdd(&bcnt[v.w >> 8], 1);
    } else {
        for (int j = 0; j < M - m; ++j) atomicAdd(&bcnt[out_idx[e + j] >> 8], 1);
    }
}

// single block: exclusive scan of bucket counts -> bbase[0..NB], bbase[NB]=E
__global__ void bscan(const int* __restrict__ bcnt, int* __restrict__ bbase, int NB, int E) {
    __shared__ int tmp[256];
    int carry = 0;
    for (int base = 0; base < NB; base += 256) {
        int i = base + threadIdx.x;
        int v = (i < NB) ? bcnt[i] : 0;
        tmp[threadIdx.x] = v;
        __syncthreads();
        for (int off = 1; off < 256; off <<= 1) {
            int t = (threadIdx.x >= off) ? tmp[threadIdx.x - off] : 0;
            __syncthreads();
            tmp[threadIdx.x] += t;
            __syncthreads();
        }
        if (i < NB) bbase[i] = tmp[threadIdx.x] - v + carry;   // exclusive
        carry += tmp[255];
        __syncthreads();
    }
    if (threadIdx.x == 0) bbase[NB] = E;
}

__global__ void init_bcursor(const int* __restrict__ bbase, int* __restrict__ bcur, int NB) {
    int b = blockIdx.x * 256 + threadIdx.x;
    if (b >= NB) return;
    bcur[b * 16] = bbase[b];
}

// ============================================================================
// passA: bucket scatter. tmp[pos] = (out&255)<<24 | k<<19 | in  (N<=2^19, K<=31)
// ============================================================================

__global__ void passA(const int* __restrict__ in_idx, const int* __restrict__ out_idx,
                      int* __restrict__ bcur, unsigned* __restrict__ tmp, int M, int NB) {
    __shared__ int cnt[NBMAX];
    __shared__ int gbase[NBMAX];
    for (int t = threadIdx.x; t < NB; t += 256) cnt[t] = 0;
    __syncthreads();
    int k = blockIdx.y;
    int base = blockIdx.x * (256 * TPT);
    unsigned pk[TPT];
    int bk[TPT];
#pragma unroll
    for (int j = 0; j < TPT; ++j) {
        int m = base + threadIdx.x + j * 256;
        if (m < M) {
            size_t e = (size_t)k * M + m;
            unsigned in = (unsigned)__builtin_nontemporal_load(in_idx + e);
            unsigned out = (unsigned)__builtin_nontemporal_load(out_idx + e);
            pk[j] = ((out & 255u) << 24) | ((unsigned)k << 19) | in;
            bk[j] = (int)(out >> 8);
            atomicAdd(&cnt[bk[j]], 1);
        } else bk[j] = -1;
    }
    __syncthreads();
    for (int b = threadIdx.x; b < NB; b += 256) {
        int c = cnt[b];
        gbase[b] = c ? atomicAdd(&bcur[b * 16], c) : 0;
        cnt[b] = 0;   // reuse as local slot cursor
    }
    __syncthreads();
#pragma unroll
    for (int j = 0; j < TPT; ++j) {
        if (bk[j] >= 0) {
            int slot = atomicAdd(&cnt[bk[j]], 1);
            tmp[gbase[bk[j]] + slot] = pk[j];
        }
    }
}

// ============================================================================
// sortK: counting-sort each bucket's segment by k (in place via LDS staging).
// Perf-only: skipped (correctly) if bucket exceeds CAPS.
// ============================================================================

__global__ void sortK(unsigned* __restrict__ tmp, const int* __restrict__ bbase) {
    __shared__ unsigned stg[CAPS];
    __shared__ int kcnt[32], kbase[32];
    int b = blockIdx.x;
    int beg = bbase[b], end = bbase[b + 1];
    int count = end - beg;
    if (count > CAPS) return;
    if (threadIdx.x < 32) kcnt[threadIdx.x] = 0;
    __syncthreads();
    for (int i = threadIdx.x; i < count; i += 256)
        atomicAdd(&kcnt[(tmp[beg + i] >> 19) & 31], 1);
    __syncthreads();
    if (threadIdx.x == 0) {
        int s = 0;
#pragma unroll
        for (int k = 0; k < 32; ++k) { kbase[k] = s; s += kcnt[k]; }
    }
    __syncthreads();
    for (int i = threadIdx.x; i < count; i += 256) {
        unsigned v = tmp[beg + i];
        int pos = atomicAdd(&kbase[(v >> 19) & 31], 1);
        stg[pos] = v;
    }
    __syncthreads();
    for (int i = threadIdx.x; i < count; i += 256)
        tmp[beg + i] = stg[i];
}

// W2T[k][d][c] = (half)W2[k][c][d]  (27 KB, L1-resident)
__global__ void transpose_W2(const float* __restrict__ W2, __half* __restrict__ W2T, int total) {
    int i = blockIdx.x * 256 + threadIdx.x;
    if (i >= total) return;
    int k = i >> 9;
    int r = i & 511;
    int c = r >> 5, d = r & 31;
    W2T[(k << 9) | (d << 4) | c] = __float2half(W2[i]);
}

// ============================================================================
// Stage 1 bucket kernel: lane-per-entry, LDS accumulate [256][17] padded
// ============================================================================

__global__ void s1_bucket(const float* __restrict__ x, const float* __restrict__ W1,
                          const float* __restrict__ g1, const float* __restrict__ b1,
                          const float* __restrict__ m1, const float* __restrict__ v1,
                          const unsigned* __restrict__ tmp, const int* __restrict__ bbase,
                          __half* __restrict__ h, int N, int K) {
    __shared__ float hacc[256 * 17];
    __shared__ float w1s[32 * 16];
    for (int t = threadIdx.x; t < 256 * 17; t += 256) hacc[t] = 0.f;
    for (int t = threadIdx.x; t < K * 16; t += 256) w1s[t] = W1[t];
    __syncthreads();
    int b = blockIdx.x;
    int beg = bbase[b], end = bbase[b + 1];
    for (int i = beg + threadIdx.x; i < end; i += 256) {
        unsigned pk = tmp[i];
        int row = pk >> 24;
        int k = (pk >> 19) & 31;
        float val = x[pk & 0x7FFFFu];
        const float* wr = &w1s[k * 16];
        float* hr = &hacc[row * 17];
#pragma unroll
        for (int c = 0; c < 16; ++c)
            atomicAdd(&hr[c], val * wr[c]);
    }
    __syncthreads();
    int r0 = b << 8;
    for (int t = threadIdx.x; t < 256 * 16; t += 256) {
        int r = t >> 4, c = t & 15;
        int row = r0 + r;
        if (row < N) {
            float scale = g1[c] * rsqrtf(v1[c] + EPSBN);
            float bias = b1[c] - m1[c] * scale;
            h[(size_t)row * 16 + c] = __float2half(elu1(hacc[r * 17 + c] * scale + bias));
        }
    }
}

// ============================================================================
// Stage 2 bucket kernel: lane-per-entry (64 random h-lines in flight/wave),
// wave-quasi-uniform W2T reads (k-sorted), LDS accumulate [256][33] padded
// ============================================================================

__global__ void s2_bucket(const __half* __restrict__ h, const __half* __restrict__ W2T,
                          const float* __restrict__ g2, const float* __restrict__ b2,
                          const float* __restrict__ m2, const float* __restrict__ v2,
                          const unsigned* __restrict__ tmp, const int* __restrict__ bbase,
                          float* __restrict__ out, int N) {
    __shared__ float acc[256 * 33];
    for (int t = threadIdx.x; t < 256 * 33; t += 256) acc[t] = 0.f;
    __syncthreads();
    int b = blockIdx.x;
    int beg = bbase[b], end = bbase[b + 1];
    for (int i = beg + threadIdx.x; i < end; i += 256) {
        unsigned pk = tmp[i];
        int row = pk >> 24;
        unsigned k = (pk >> 19) & 31;
        const float4* hp = (const float4*)(h + ((size_t)(pk & 0x7FFFFu) << 4));
        float4 h0 = hp[0], h1 = hp[1];
        const float4* wp = (const float4*)(W2T + ((size_t)k << 9));
        float* ar = &acc[row * 33];
#pragma unroll 8
        for (int d = 0; d < 32; ++d) {
            float a = dot8h(h0, wp[d * 2], 0.f);
            a = dot8h(h1, wp[d * 2 + 1], a);
            atomicAdd(&ar[d], a);
        }
    }
    __syncthreads();
    int r0 = b << 8;
    for (int t = threadIdx.x; t < 256 * 32; t += 256) {
        int r = t >> 5, d = t & 31;
        int row = r0 + r;
        if (row < N) {
            float scale = g2[d] * rsqrtf(v2[d] + EPSBN);
            float bias = b2[d] - m2[d] * scale;
            out[(size_t)row * 32 + d] = elu1(acc[r * 33 + d] * scale + bias);
        }
    }
}

// ============================================================================
// Last-resort fallback: atomic path (fp32 throughout)
// ============================================================================

__global__ void s1_scatter_slab(const float* __restrict__ x, const int* __restrict__ in_idx,
                                const int* __restrict__ out_idx, float* __restrict__ s, int M, int N) {
    int m = blockIdx.x * blockDim.x + threadIdx.x;
    if (m >= M) return;
    int k = blockIdx.y;
    size_t e = (size_t)k * M + m;
    unsafeAtomicAdd(&s[(size_t)k * N + out_idx[e]], x[in_idx[e]]);
}

__global__ void s1_combine(const float* __restrict__ s, const float* __restrict__ W1,
                           const float* __restrict__ g1, const float* __restrict__ b1,
                           const float* __restrict__ m1, const float* __restrict__ v1,
                           float* __restrict__ h, int N, int K) {
    __shared__ float w[32 * 16];
    __shared__ float sc[16], bi[16];
    for (int t = threadIdx.x; t < K * 16; t += blockDim.x) w[t] = W1[t];
    if (threadIdx.x < 16) {
        float scale = g1[threadIdx.x] * rsqrtf(v1[threadIdx.x] + EPSBN);
        sc[threadIdx.x] = scale;
        bi[threadIdx.x] = b1[threadIdx.x] - m1[threadIdx.x] * scale;
    }
    __syncthreads();
    int n = blockIdx.x * blockDim.x + threadIdx.x;
    if (n >= N) return;
    float acc[16];
#pragma unroll
    for (int c = 0; c < 16; ++c) acc[c] = 0.f;
    for (int k = 0; k < K; ++k) {
        float sv = s[(size_t)k * N + n];
#pragma unroll
        for (int c = 0; c < 16; ++c) acc[c] = fmaf(sv, w[k * 16 + c], acc[c]);
    }
    float4* hv = (float4*)(h + (size_t)n * 16);
#pragma unroll
    for (int q = 0; q < 4; ++q) {
        float4 o;
        o.x = elu1(acc[q * 4 + 0] * sc[q * 4 + 0] + bi[q * 4 + 0]);
        o.y = elu1(acc[q * 4 + 1] * sc[q * 4 + 1] + bi[q * 4 + 1]);
        o.z = elu1(acc[q * 4 + 2] * sc[q * 4 + 2] + bi[q * 4 + 2]);
        o.w = elu1(acc[q * 4 + 3] * sc[q * 4 + 3] + bi[q * 4 + 3]);
        hv[q] = o;
    }
}

__global__ void bn_elu_c(float* __restrict__ buf, const float* __restrict__ g,
                         const float* __restrict__ b, const float* __restrict__ m,
                         const float* __restrict__ v, size_t total, int cmask) {
    size_t i = (size_t)blockIdx.x * blockDim.x + threadIdx.x;
    if (i >= total) return;
    int c = (int)(i & (size_t)cmask);
    float scale = g[c] * rsqrtf(v[c] + EPSBN);
    buf[i] = elu1((buf[i] - m[c]) * scale + b[c]);
}

__global__ void s2_scatter(const float* __restrict__ h, const float* __restrict__ W2,
                           const int* __restrict__ in_idx, const int* __restrict__ out_idx,
                           float* __restrict__ acc, int M) {
    __shared__ float w[16 * 32];
    int k = blockIdx.y;
    for (int t = threadIdx.x; t < 512; t += blockDim.x) w[t] = W2[(size_t)k * 512 + t];
    __syncthreads();
    int m = blockIdx.x * blockDim.x + threadIdx.x;
    if (m >= M) return;
    size_t e = (size_t)k * M + m;
    int in = in_idx[e], out = out_idx[e];
    const float4* hr = (const float4*)(h + (size_t)in * 16);
    float4 h0 = hr[0], h1 = hr[1], h2 = hr[2], h3 = hr[3];
    float hrow[16] = {h0.x, h0.y, h0.z, h0.w, h1.x, h1.y, h1.z, h1.w,
                      h2.x, h2.y, h2.z, h2.w, h3.x, h3.y, h3.z, h3.w};
    float yv[32];
#pragma unroll
    for (int dd = 0; dd < 32; ++dd) yv[dd] = 0.f;
#pragma unroll
    for (int c = 0; c < 16; ++c) {
        float hv = hrow[c];
#pragma unroll
        for (int dd = 0; dd < 32; ++dd) yv[dd] = fmaf(hv, w[c * 32 + dd], yv[dd]);
    }
    float* ar = acc + (size_t)out * 32;
#pragma unroll
    for (int dd = 0; dd < 32; ++dd) unsafeAtomicAdd(&ar[dd], yv[dd]);
}

// ============================================================================

extern "C" void kernel_launch(void* const* d_in, const int* in_sizes, int n_in,
                              void* d_out, int out_size, void* d_ws, size_t ws_size,
                              hipStream_t stream) {
    const float* x  = (const float*)d_in[0];
    const float* W1 = (const float*)d_in[1];
    const float* g1 = (const float*)d_in[2];
    const float* b1 = (const float*)d_in[3];
    const float* m1 = (const float*)d_in[4];
    const float* v1 = (const float*)d_in[5];
    const float* W2 = (const float*)d_in[6];
    const float* g2 = (const float*)d_in[7];
    const float* b2 = (const float*)d_in[8];
    const float* m2 = (const float*)d_in[9];
    const float* v2 = (const float*)d_in[10];
    const int* in_idx  = (const int*)d_in[11];
    const int* out_idx = (const int*)d_in[12];

    const int N  = in_sizes[0];
    const int C1 = in_sizes[2];           // 16
    const int K  = in_sizes[1] / C1;      // 27
    const int M  = in_sizes[11] / K;      // 200000
    const int E  = K * M;                 // 5.4M
    const int NB = (N + 255) >> 8;        // buckets (256 rows each)

    float* out = (float*)d_out;
    dim3 blk(256);
    dim3 grdKM((M + 255) / 256, K);

    auto align256 = [](size_t v) { return (v + 255) & ~(size_t)255; };
    size_t bcntB  = align256((size_t)NB * 4);
    size_t bbaseB = align256((size_t)(NB + 1) * 4);
    size_t bcurB  = align256((size_t)NB * 16 * 4);
    size_t tmpB   = align256((size_t)E * 4);
    size_t w2tB   = align256((size_t)K * 512 * 2);
    size_t hB     = align256((size_t)N * 16 * 2);
    size_t need   = bcntB + bbaseB + bcurB + tmpB + w2tB + hB;

    bool canRadix = (N <= (1 << 19)) && (K <= 31) && (NB <= NBMAX) && (ws_size >= need);

    if (canRadix) {
        char* p = (char*)d_ws;
        int* bcnt       = (int*)p;            p += bcntB;
        int* bbase      = (int*)p;            p += bbaseB;
        int* bcur       = (int*)p;            p += bcurB;
        unsigned* tmp   = (unsigned*)p;       p += tmpB;
        __half* W2T     = (__half*)p;         p += w2tB;
        __half* h       = (__half*)p;

        hipMemsetAsync(bcnt, 0, (size_t)NB * 4, stream);
        bhist<<<dim3((M / 4 + 256) / 256, K), blk, 0, stream>>>(out_idx, bcnt, M);
        transpose_W2<<<dim3((K * 512 + 255) / 256), blk, 0, stream>>>(W2, W2T, K * 512);
        bscan<<<dim3(1), blk, 0, stream>>>(bcnt, bbase, NB, E);
        init_bcursor<<<dim3((NB + 255) / 256), blk, 0, stream>>>(bbase, bcur, NB);
        passA<<<dim3((M + 256 * TPT - 1) / (256 * TPT), K), blk, 0, stream>>>(in_idx, out_idx, bcur, tmp, M, NB);
        sortK<<<dim3(NB), blk, 0, stream>>>(tmp, bbase);
        s1_bucket<<<dim3(NB), blk, 0, stream>>>(x, W1, g1, b1, m1, v1, tmp, bbase, h, N, K);
        s2_bucket<<<dim3(NB), blk, 0, stream>>>(h, W2T, g2, b2, m2, v2, tmp, bbase, out, N);
        return;
    }

    // ---------------- fallback: atomic path ----------------
    size_t sBytes = align256((size_t)K * N * 4);
    size_t hBytes = (size_t)N * 16 * 4;
    float* hf = (float*)d_ws;
    if (ws_size >= sBytes + hBytes) {
        float* s = (float*)d_ws;
        hf = (float*)((char*)d_ws + sBytes);
        hipMemsetAsync(s, 0, (size_t)K * N * 4, stream);
        s1_scatter_slab<<<grdKM, blk, 0, stream>>>(x, in_idx, out_idx, s, M, N);
        s1_combine<<<dim3((N + 255) / 256), blk, 0, stream>>>(s, W1, g1, b1, m1, v1, hf, N, K);
    }
    hipMemsetAsync(out, 0, (size_t)N * 32 * 4, stream);
    s2_scatter<<<grdKM, blk, 0, stream>>>(hf, W2, in_idx, out_idx, out, M);
    size_t tot2 = (size_t)N * 32;
    bn_elu_c<<<dim3((unsigned)((tot2 + 255) / 256)), blk, 0, stream>>>(out, g2, b2, m2, v2, tot2, 31);
}

// Round 10
// 623.126 us; speedup vs baseline: 3.9214x; 3.9214x over previous
//
#include <hip/hip_runtime.h>
#include <hip/hip_fp16.h>
#include <math.h>

#define EPSBN 1e-5f
#define NBMAX 2048          // max buckets (256 rows each) for radix path
#define TPT 32              // entries per thread in passA
#define CAPB 8192           // passB LDS staging capacity (entries)

__device__ __forceinline__ float elu1(float x) { return x > 0.f ? x : expm1f(x); }

// dot of 8 half pairs (packed in float4 bit patterns), fp32 accumulate
__device__ __forceinline__ float dot8h(float4 hv, float4 wv, float acc) {
#if defined(__has_builtin)
#if __has_builtin(__builtin_amdgcn_fdot2)
    typedef _Float16 h2v __attribute__((ext_vector_type(2)));
    union { float4 f; h2v h[4]; } a, b;
    a.f = hv; b.f = wv;
#pragma unroll
    for (int i = 0; i < 4; ++i)
        acc = __builtin_amdgcn_fdot2(a.h[i], b.h[i], acc, false);
    return acc;
#endif
#endif
    const __half2* ha = (const __half2*)&hv;
    const __half2* wa = (const __half2*)&wv;
#pragma unroll
    for (int i = 0; i < 4; ++i) {
        float2 hf = __half22float2(ha[i]);
        float2 wf = __half22float2(wa[i]);
        acc = fmaf(hf.x, wf.x, acc);
        acc = fmaf(hf.y, wf.y, acc);
    }
    return acc;
}

// ============================================================================
// CSR build part 1: per-row histogram + offsets (round-5 known-good forms)
// ============================================================================

__global__ void hist_kernel(const int* __restrict__ out_idx, int* __restrict__ cnt, int M) {
    int m = blockIdx.x * blockDim.x + threadIdx.x;
    if (m >= M) return;
    size_t e = (size_t)blockIdx.y * M + m;
    atomicAdd(&cnt[out_idx[e]], 1);
}

__global__ void scan_block_sums(const int* __restrict__ cnt, int* __restrict__ bsum, int N) {
    __shared__ int tmp[256];
    int i = blockIdx.x * 256 + threadIdx.x;
    tmp[threadIdx.x] = (i < N) ? cnt[i] : 0;
    __syncthreads();
    for (int off = 128; off > 0; off >>= 1) {
        if (threadIdx.x < off) tmp[threadIdx.x] += tmp[threadIdx.x + off];
        __syncthreads();
    }
    if (threadIdx.x == 0) bsum[blockIdx.x] = tmp[0];
}

__global__ void scan_bsums(int* __restrict__ bsum, int nb, int* __restrict__ offsets, int N, int E) {
    __shared__ int tmp[256];
    int carry = 0;
    for (int base = 0; base < nb; base += 256) {
        int i = base + threadIdx.x;
        int v = (i < nb) ? bsum[i] : 0;
        tmp[threadIdx.x] = v;
        __syncthreads();
        for (int off = 1; off < 256; off <<= 1) {
            int t = (threadIdx.x >= off) ? tmp[threadIdx.x - off] : 0;
            __syncthreads();
            tmp[threadIdx.x] += t;
            __syncthreads();
        }
        int incl = tmp[threadIdx.x];
        int total = tmp[255];
        if (i < nb) bsum[i] = incl - v + carry;   // exclusive
        carry += total;
        __syncthreads();
    }
    if (threadIdx.x == 0) offsets[N] = E;
}

__global__ void scan_final(const int* __restrict__ cnt, const int* __restrict__ bsum,
                           int* __restrict__ offsets, int* __restrict__ cursor, int N) {
    __shared__ int tmp[256];
    int i = blockIdx.x * 256 + threadIdx.x;
    int v = (i < N) ? cnt[i] : 0;
    tmp[threadIdx.x] = v;
    __syncthreads();
    for (int off = 1; off < 256; off <<= 1) {
        int t = (threadIdx.x >= off) ? tmp[threadIdx.x - off] : 0;
        __syncthreads();
        tmp[threadIdx.x] += t;
        __syncthreads();
    }
    if (i < N) {
        int o = tmp[threadIdx.x] - v + bsum[blockIdx.x];
        offsets[i] = o;
        cursor[i] = o;
    }
}

// ============================================================================
// CSR build part 2a (radix path): bucket scatter. bucket = out >> 8.
// tmp[pos] = (out&255)<<24 | k<<19 | in   (requires N<=2^19, K<=32)
// ============================================================================

__global__ void init_bcursor(const int* __restrict__ offsets, int* __restrict__ bcur, int NB, int N) {
    int b = blockIdx.x * 256 + threadIdx.x;
    if (b >= NB) return;
    int row = b << 8; if (row > N) row = N;
    bcur[b * 16] = offsets[row];
}

__global__ void passA(const int* __restrict__ in_idx, const int* __restrict__ out_idx,
                      int* __restrict__ bcur, unsigned* __restrict__ tmp, int M, int NB) {
    __shared__ int cnt[NBMAX];
    __shared__ int gbase[NBMAX];
    for (int t = threadIdx.x; t < NB; t += 256) cnt[t] = 0;
    __syncthreads();
    int k = blockIdx.y;
    int base = blockIdx.x * (256 * TPT);
    unsigned pk[TPT];
    int bk[TPT];
#pragma unroll
    for (int j = 0; j < TPT; ++j) {
        int m = base + threadIdx.x + j * 256;
        if (m < M) {
            size_t e = (size_t)k * M + m;
            unsigned in = (unsigned)in_idx[e];
            unsigned out = (unsigned)out_idx[e];
            pk[j] = ((out & 255u) << 24) | ((unsigned)k << 19) | in;
            bk[j] = (int)(out >> 8);
            atomicAdd(&cnt[bk[j]], 1);
        } else bk[j] = -1;
    }
    __syncthreads();
    for (int b = threadIdx.x; b < NB; b += 256) {
        int c = cnt[b];
        gbase[b] = c ? atomicAdd(&bcur[b * 16], c) : 0;
        cnt[b] = 0;   // reuse as local slot cursor
    }
    __syncthreads();
#pragma unroll
    for (int j = 0; j < TPT; ++j) {
        if (bk[j] >= 0) {
            int slot = atomicAdd(&cnt[bk[j]], 1);
            tmp[gbase[bk[j]] + slot] = pk[j];
        }
    }
}

// Pass B: one block per bucket; counting-sort bucket into LDS, coalesced write.
__global__ void passB(const unsigned* __restrict__ tmp, const int* __restrict__ offsets,
                      unsigned* __restrict__ entries, int N) {
    __shared__ int cur[256];
    __shared__ unsigned stg[CAPB];
    int b = blockIdx.x;
    int r0 = b << 8;
    int rend = r0 + 256; if (rend > N) rend = N;
    int nr = rend - r0;
    int gbeg = offsets[r0];
    int gend = offsets[rend];
    int count = gend - gbeg;
    if (threadIdx.x < nr) cur[threadIdx.x] = offsets[r0 + threadIdx.x] - gbeg;
    __syncthreads();
    if (count <= CAPB) {
        for (int i = threadIdx.x; i < count; i += 256) {
            unsigned v = tmp[gbeg + i];
            int slot = atomicAdd(&cur[v >> 24], 1);
            stg[slot] = v & 0x00FFFFFFu;
        }
        __syncthreads();
        for (int i = threadIdx.x; i < count; i += 256)
            entries[gbeg + i] = stg[i];
    } else {
        for (int i = threadIdx.x; i < count; i += 256) {
            unsigned v = tmp[gbeg + i];
            int slot = atomicAdd(&cur[v >> 24], 1);
            entries[gbeg + slot] = v & 0x00FFFFFFu;
        }
    }
}

// ============================================================================
// CSR build part 2b (fallback): direct atomic scatter
// ============================================================================

__global__ void scatter_entries(const int* __restrict__ in_idx, const int* __restrict__ out_idx,
                                int* __restrict__ cursor, unsigned* __restrict__ entries, int M, int shift) {
    int m = blockIdx.x * blockDim.x + threadIdx.x;
    if (m >= M) return;
    int k = blockIdx.y;
    size_t e = (size_t)k * M + m;
    int pos = atomicAdd(&cursor[out_idx[e]], 1);
    entries[pos] = (unsigned)in_idx[e] | ((unsigned)k << shift);
}

// W2T[k][d][c] = (half)W2[k][c][d]  (27 KB, L1-resident)
__global__ void transpose_W2(const float* __restrict__ W2, __half* __restrict__ W2T, int total) {
    int i = blockIdx.x * 256 + threadIdx.x;
    if (i >= total) return;
    int k = i >> 9;
    int r = i & 511;
    int c = r >> 5, d = r & 31;
    W2T[(k << 9) | (d << 4) | c] = __float2half(W2[i]);
}

// ============================================================================
// Stage 1 gather: 16 threads per row, broadcast entry loads, fp16 h out
// ============================================================================

__global__ void s1_gather_f16(const float* __restrict__ x, const float* __restrict__ W1,
                              const float* __restrict__ g1, const float* __restrict__ b1,
                              const float* __restrict__ m1, const float* __restrict__ v1,
                              const int* __restrict__ offsets, const unsigned* __restrict__ entries,
                              __half* __restrict__ h, int N, int shift, unsigned mask) {
    int row = blockIdx.x * 16 + (threadIdx.x >> 4);
    int c = threadIdx.x & 15;
    if (row >= N) return;
    int beg = offsets[row], end = offsets[row + 1];
    float acc = 0.f;
    for (int base = beg; base < end; base += 16) {
        int cnt = end - base; if (cnt > 16) cnt = 16;
        unsigned ev = entries[base + (c < cnt ? c : cnt - 1)];
        int j = 0;
        for (; j + 1 < cnt; j += 2) {
            unsigned pk0 = __shfl(ev, j, 16);
            unsigned pk1 = __shfl(ev, j + 1, 16);
            float x0 = x[pk0 & mask];
            float x1 = x[pk1 & mask];
            acc = fmaf(x0, W1[(pk0 >> shift) * 16 + c], acc);
            acc = fmaf(x1, W1[(pk1 >> shift) * 16 + c], acc);
        }
        if (j < cnt) {
            unsigned pk0 = __shfl(ev, j, 16);
            acc = fmaf(x[pk0 & mask], W1[(pk0 >> shift) * 16 + c], acc);
        }
    }
    float scale = g1[c] * rsqrtf(v1[c] + EPSBN);
    float bias = b1[c] - m1[c] * scale;
    h[(size_t)row * 16 + c] = __float2half(elu1(acc * scale + bias));
}

// ============================================================================
// Stage 2 gather v2: one half-wave per row. Per 32-entry chunk: lane j
// cooperatively loads entry j's h-row (32 random lines in flight/half-wave)
// -> LDS staging -> wave waitcnt -> register-accumulated dot loop (no atomics).
// ============================================================================

__global__ void s2_gather_v2(const __half* __restrict__ h, const __half* __restrict__ W2T,
                             const float* __restrict__ g2, const float* __restrict__ b2,
                             const float* __restrict__ m2, const float* __restrict__ v2,
                             const int* __restrict__ offsets, const unsigned* __restrict__ entries,
                             float* __restrict__ out, int N, int shift, unsigned mask) {
    __shared__ __half stg[8][32 * 16 + 8];   // 1KB staging per half-wave (+pad)
    int hw = threadIdx.x >> 5;
    int lane = threadIdx.x & 31;
    int row = blockIdx.x * 8 + hw;
    if (row >= N) return;
    int d = lane;
    int beg = offsets[row], end = offsets[row + 1];
    float acc = 0.f;
    __half* my = stg[hw];
    for (int base = beg; base < end; base += 32) {
        int cnt = end - base; if (cnt > 32) cnt = 32;
        unsigned ev = entries[base + (lane < cnt ? lane : cnt - 1)];
        if (lane < cnt) {
            const float4* hp = (const float4*)(h + ((size_t)(ev & mask) << 4));
            float4 h0 = hp[0], h1 = hp[1];
            float4* dst = (float4*)(my + lane * 16);
            dst[0] = h0;
            dst[1] = h1;
        }
        // wave-lockstep: drain LDS writes before cross-lane reads
        asm volatile("s_waitcnt lgkmcnt(0)" ::: "memory");
        int j = 0;
        for (; j + 1 < cnt; j += 2) {
            unsigned pk0 = __shfl(ev, j, 32);
            unsigned pk1 = __shfl(ev, j + 1, 32);
            const float4* hr0 = (const float4*)(my + j * 16);
            const float4* hr1 = (const float4*)(my + (j + 1) * 16);
            float4 ha0 = hr0[0], hb0 = hr0[1];
            float4 ha1 = hr1[0], hb1 = hr1[1];
            const float4* wp0 = (const float4*)(W2T + (((size_t)(pk0 >> shift) << 9) | ((unsigned)d << 4)));
            const float4* wp1 = (const float4*)(W2T + (((size_t)(pk1 >> shift) << 9) | ((unsigned)d << 4)));
            acc = dot8h(ha0, wp0[0], acc);
            acc = dot8h(hb0, wp0[1], acc);
            acc = dot8h(ha1, wp1[0], acc);
            acc = dot8h(hb1, wp1[1], acc);
        }
        if (j < cnt) {
            unsigned pk0 = __shfl(ev, j, 32);
            const float4* hr0 = (const float4*)(my + j * 16);
            float4 ha0 = hr0[0], hb0 = hr0[1];
            const float4* wp0 = (const float4*)(W2T + (((size_t)(pk0 >> shift) << 9) | ((unsigned)d << 4)));
            acc = dot8h(ha0, wp0[0], acc);
            acc = dot8h(hb0, wp0[1], acc);
        }
        // ensure this chunk's reads done before next chunk overwrites staging
        asm volatile("s_waitcnt lgkmcnt(0)" ::: "memory");
    }
    float scale = g2[d] * rsqrtf(v2[d] + EPSBN);
    float bias = b2[d] - m2[d] * scale;
    out[(size_t)row * 32 + d] = elu1(acc * scale + bias);
}

// ============================================================================
// Last-resort fallback: atomic path (fp32 throughout)
// ============================================================================

__global__ void s1_scatter_slab(const float* __restrict__ x, const int* __restrict__ in_idx,
                                const int* __restrict__ out_idx, float* __restrict__ s, int M, int N) {
    int m = blockIdx.x * blockDim.x + threadIdx.x;
    if (m >= M) return;
    int k = blockIdx.y;
    size_t e = (size_t)k * M + m;
    unsafeAtomicAdd(&s[(size_t)k * N + out_idx[e]], x[in_idx[e]]);
}

__global__ void s1_combine(const float* __restrict__ s, const float* __restrict__ W1,
                           const float* __restrict__ g1, const float* __restrict__ b1,
                           const float* __restrict__ m1, const float* __restrict__ v1,
                           float* __restrict__ h, int N, int K) {
    __shared__ float w[32 * 16];
    __shared__ float sc[16], bi[16];
    for (int t = threadIdx.x; t < K * 16; t += blockDim.x) w[t] = W1[t];
    if (threadIdx.x < 16) {
        float scale = g1[threadIdx.x] * rsqrtf(v1[threadIdx.x] + EPSBN);
        sc[threadIdx.x] = scale;
        bi[threadIdx.x] = b1[threadIdx.x] - m1[threadIdx.x] * scale;
    }
    __syncthreads();
    int n = blockIdx.x * blockDim.x + threadIdx.x;
    if (n >= N) return;
    float acc[16];
#pragma unroll
    for (int c = 0; c < 16; ++c) acc[c] = 0.f;
    for (int k = 0; k < K; ++k) {
        float sv = s[(size_t)k * N + n];
#pragma unroll
        for (int c = 0; c < 16; ++c) acc[c] = fmaf(sv, w[k * 16 + c], acc[c]);
    }
    float4* hv = (float4*)(h + (size_t)n * 16);
#pragma unroll
    for (int q = 0; q < 4; ++q) {
        float4 o;
        o.x = elu1(acc[q * 4 + 0] * sc[q * 4 + 0] + bi[q * 4 + 0]);
        o.y = elu1(acc[q * 4 + 1] * sc[q * 4 + 1] + bi[q * 4 + 1]);
        o.z = elu1(acc[q * 4 + 2] * sc[q * 4 + 2] + bi[q * 4 + 2]);
        o.w = elu1(acc[q * 4 + 3] * sc[q * 4 + 3] + bi[q * 4 + 3]);
        hv[q] = o;
    }
}

__global__ void bn_elu_c(float* __restrict__ buf, const float* __restrict__ g,
                         const float* __restrict__ b, const float* __restrict__ m,
                         const float* __restrict__ v, size_t total, int cmask) {
    size_t i = (size_t)blockIdx.x * blockDim.x + threadIdx.x;
    if (i >= total) return;
    int c = (int)(i & (size_t)cmask);
    float scale = g[c] * rsqrtf(v[c] + EPSBN);
    buf[i] = elu1((buf[i] - m[c]) * scale + b[c]);
}

__global__ void s2_scatter(const float* __restrict__ h, const float* __restrict__ W2,
                           const int* __restrict__ in_idx, const int* __restrict__ out_idx,
                           float* __restrict__ acc, int M) {
    __shared__ float w[16 * 32];
    int k = blockIdx.y;
    for (int t = threadIdx.x; t < 512; t += blockDim.x) w[t] = W2[(size_t)k * 512 + t];
    __syncthreads();
    int m = blockIdx.x * blockDim.x + threadIdx.x;
    if (m >= M) return;
    size_t e = (size_t)k * M + m;
    int in = in_idx[e], out = out_idx[e];
    const float4* hr = (const float4*)(h + (size_t)in * 16);
    float4 h0 = hr[0], h1 = hr[1], h2 = hr[2], h3 = hr[3];
    float hrow[16] = {h0.x, h0.y, h0.z, h0.w, h1.x, h1.y, h1.z, h1.w,
                      h2.x, h2.y, h2.z, h2.w, h3.x, h3.y, h3.z, h3.w};
    float yv[32];
#pragma unroll
    for (int dd = 0; dd < 32; ++dd) yv[dd] = 0.f;
#pragma unroll
    for (int c = 0; c < 16; ++c) {
        float hv = hrow[c];
#pragma unroll
        for (int dd = 0; dd < 32; ++dd) yv[dd] = fmaf(hv, w[c * 32 + dd], yv[dd]);
    }
    float* ar = acc + (size_t)out * 32;
#pragma unroll
    for (int dd = 0; dd < 32; ++dd) unsafeAtomicAdd(&ar[dd], yv[dd]);
}

// ============================================================================

extern "C" void kernel_launch(void* const* d_in, const int* in_sizes, int n_in,
                              void* d_out, int out_size, void* d_ws, size_t ws_size,
                              hipStream_t stream) {
    const float* x  = (const float*)d_in[0];
    const float* W1 = (const float*)d_in[1];
    const float* g1 = (const float*)d_in[2];
    const float* b1 = (const float*)d_in[3];
    const float* m1 = (const float*)d_in[4];
    const float* v1 = (const float*)d_in[5];
    const float* W2 = (const float*)d_in[6];
    const float* g2 = (const float*)d_in[7];
    const float* b2 = (const float*)d_in[8];
    const float* m2 = (const float*)d_in[9];
    const float* v2 = (const float*)d_in[10];
    const int* in_idx  = (const int*)d_in[11];
    const int* out_idx = (const int*)d_in[12];

    const int N  = in_sizes[0];
    const int C1 = in_sizes[2];           // 16
    const int K  = in_sizes[1] / C1;      // 27
    const int M  = in_sizes[11] / K;      // 200000
    const int E  = K * M;                 // 5.4M
    const int nb = (N + 255) / 256;
    const int NB = (N + 255) >> 8;        // radix buckets (256 rows each)

    float* out = (float*)d_out;
    dim3 blk(256);
    dim3 grdKM((M + 255) / 256, K);

    auto align256 = [](size_t v) { return (v + 255) & ~(size_t)255; };
    size_t cntB   = align256((size_t)N * 4);
    size_t offB   = align256((size_t)(N + 1) * 4);
    size_t bsumB  = align256((size_t)nb * 4);
    size_t entB   = align256((size_t)E * 4);
    size_t w2tB   = align256((size_t)K * 512 * 2);
    size_t hB     = align256((size_t)N * 16 * 2);
    size_t baseNeed = cntB + offB + bsumB + entB + w2tB + hB;

    size_t bcurB  = align256((size_t)NB * 16 * 4);
    size_t tmpB   = align256((size_t)E * 4);
    size_t curB   = align256((size_t)N * 4);

    bool canCSR   = (N < (1 << 24)) && (K < 256);
    bool canRadix = (N <= (1 << 19)) && (K <= 32) && (NB <= NBMAX) &&
                    (ws_size >= baseNeed + bcurB + tmpB + curB);

    if (canCSR && ws_size >= baseNeed + curB) {
        char* p = (char*)d_ws;
        int* cnt        = (int*)p;            p += cntB;
        int* offsets    = (int*)p;            p += offB;
        int* bsum       = (int*)p;            p += bsumB;
        unsigned* ent   = (unsigned*)p;       p += entB;
        __half* W2T     = (__half*)p;         p += w2tB;
        __half* h       = (__half*)p;         p += hB;
        int* cursor     = (int*)p;            p += curB;

        const int shift = canRadix ? 19 : 24;
        const unsigned mask = canRadix ? 0x7FFFFu : 0xFFFFFFu;

        hipMemsetAsync(cnt, 0, (size_t)N * 4, stream);
        hist_kernel<<<grdKM, blk, 0, stream>>>(out_idx, cnt, M);
        transpose_W2<<<dim3((K * 512 + 255) / 256), blk, 0, stream>>>(W2, W2T, K * 512);
        scan_block_sums<<<dim3(nb), blk, 0, stream>>>(cnt, bsum, N);
        scan_bsums<<<dim3(1), blk, 0, stream>>>(bsum, nb, offsets, N, E);
        scan_final<<<dim3(nb), blk, 0, stream>>>(cnt, bsum, offsets, cursor, N);

        if (canRadix) {
            int* bcur     = (int*)p;          p += bcurB;
            unsigned* tmp = (unsigned*)p;
            init_bcursor<<<dim3((NB + 255) / 256), blk, 0, stream>>>(offsets, bcur, NB, N);
            passA<<<dim3((M + 256 * TPT - 1) / (256 * TPT), K), blk, 0, stream>>>(in_idx, out_idx, bcur, tmp, M, NB);
            passB<<<dim3(NB), blk, 0, stream>>>(tmp, offsets, ent, N);
        } else {
            scatter_entries<<<grdKM, blk, 0, stream>>>(in_idx, out_idx, cursor, ent, M, shift);
        }

        s1_gather_f16<<<dim3((N + 15) / 16), blk, 0, stream>>>(x, W1, g1, b1, m1, v1, offsets, ent, h, N, shift, mask);
        s2_gather_v2<<<dim3((N + 7) / 8), blk, 0, stream>>>(h, W2T, g2, b2, m2, v2, offsets, ent, out, N, shift, mask);
        return;
    }

    // ---------------- fallback: atomic path ----------------
    size_t sBytes = align256((size_t)K * N * 4);
    size_t hBytes = (size_t)N * 16 * 4;
    float* hf = (float*)d_ws;
    if (ws_size >= sBytes + hBytes) {
        float* s = (float*)d_ws;
        hf = (float*)((char*)d_ws + sBytes);
        hipMemsetAsync(s, 0, (size_t)K * N * 4, stream);
        s1_scatter_slab<<<grdKM, blk, 0, stream>>>(x, in_idx, out_idx, s, M, N);
        s1_combine<<<dim3((N + 255) / 256), blk, 0, stream>>>(s, W1, g1, b1, m1, v1, hf, N, K);
    }
    hipMemsetAsync(out, 0, (size_t)N * 32 * 4, stream);
    s2_scatter<<<grdKM, blk, 0, stream>>>(hf, W2, in_idx, out_idx, out, M);
    size_t tot2 = (size_t)N * 32;
    bn_elu_c<<<dim3((unsigned)((tot2 + 255) / 256)), blk, 0, stream>>>(out, g2, b2, m2, v2, tot2, 31);
}

// Round 11
// 620.658 us; speedup vs baseline: 3.9370x; 1.0040x over previous
//
#include <hip/hip_runtime.h>
#include <hip/hip_fp16.h>
#include <math.h>

#define EPSBN 1e-5f
#define NBMAX 2048          // max buckets (256 rows each) for radix path
#define TPT 32              // entries per thread in passA
#define CAPB 8192           // passB LDS staging capacity (entries)

typedef int int4v __attribute__((ext_vector_type(4)));

__device__ __forceinline__ float elu1(float x) { return x > 0.f ? x : expm1f(x); }

// dot of 8 half pairs (packed in float4 bit patterns), fp32 accumulate
__device__ __forceinline__ float dot8h(float4 hv, float4 wv, float acc) {
#if defined(__has_builtin)
#if __has_builtin(__builtin_amdgcn_fdot2)
    typedef _Float16 h2v __attribute__((ext_vector_type(2)));
    union { float4 f; h2v h[4]; } a, b;
    a.f = hv; b.f = wv;
#pragma unroll
    for (int i = 0; i < 4; ++i)
        acc = __builtin_amdgcn_fdot2(a.h[i], b.h[i], acc, false);
    return acc;
#endif
#endif
    const __half2* ha = (const __half2*)&hv;
    const __half2* wa = (const __half2*)&wv;
#pragma unroll
    for (int i = 0; i < 4; ++i) {
        float2 hf = __half22float2(ha[i]);
        float2 wf = __half22float2(wa[i]);
        acc = fmaf(hf.x, wf.x, acc);
        acc = fmaf(hf.y, wf.y, acc);
    }
    return acc;
}

// ============================================================================
// CSR build part 1: per-row histogram + offsets
// ============================================================================

__global__ void hist_kernel(const int* __restrict__ out_idx, int* __restrict__ cnt, int M) {
    int m = (blockIdx.x * blockDim.x + threadIdx.x) * 4;
    if (m >= M) return;
    size_t e = (size_t)blockIdx.y * M + m;
    if (m + 3 < M) {
        int4v v = *(const int4v*)(out_idx + e);
        atomicAdd(&cnt[v.x], 1);
        atomicAdd(&cnt[v.y], 1);
        atomicAdd(&cnt[v.z], 1);
        atomicAdd(&cnt[v.w], 1);
    } else {
        for (int j = 0; j < M - m; ++j) atomicAdd(&cnt[out_idx[e + j]], 1);
    }
}

__global__ void scan_block_sums(const int* __restrict__ cnt, int* __restrict__ bsum, int N) {
    __shared__ int tmp[256];
    int i = blockIdx.x * 256 + threadIdx.x;
    tmp[threadIdx.x] = (i < N) ? cnt[i] : 0;
    __syncthreads();
    for (int off = 128; off > 0; off >>= 1) {
        if (threadIdx.x < off) tmp[threadIdx.x] += tmp[threadIdx.x + off];
        __syncthreads();
    }
    if (threadIdx.x == 0) bsum[blockIdx.x] = tmp[0];
}

__global__ void scan_bsums(int* __restrict__ bsum, int nb, int* __restrict__ offsets, int N, int E) {
    __shared__ int tmp[256];
    int carry = 0;
    for (int base = 0; base < nb; base += 256) {
        int i = base + threadIdx.x;
        int v = (i < nb) ? bsum[i] : 0;
        tmp[threadIdx.x] = v;
        __syncthreads();
        for (int off = 1; off < 256; off <<= 1) {
            int t = (threadIdx.x >= off) ? tmp[threadIdx.x - off] : 0;
            __syncthreads();
            tmp[threadIdx.x] += t;
            __syncthreads();
        }
        int incl = tmp[threadIdx.x];
        int total = tmp[255];
        if (i < nb) bsum[i] = incl - v + carry;   // exclusive
        carry += total;
        __syncthreads();
    }
    if (threadIdx.x == 0) offsets[N] = E;
}

__global__ void scan_final(const int* __restrict__ cnt, const int* __restrict__ bsum,
                           int* __restrict__ offsets, int* __restrict__ cursor, int N) {
    __shared__ int tmp[256];
    int i = blockIdx.x * 256 + threadIdx.x;
    int v = (i < N) ? cnt[i] : 0;
    tmp[threadIdx.x] = v;
    __syncthreads();
    for (int off = 1; off < 256; off <<= 1) {
        int t = (threadIdx.x >= off) ? tmp[threadIdx.x - off] : 0;
        __syncthreads();
        tmp[threadIdx.x] += t;
        __syncthreads();
    }
    if (i < N) {
        int o = tmp[threadIdx.x] - v + bsum[blockIdx.x];
        offsets[i] = o;
        cursor[i] = o;
    }
}

// ============================================================================
// CSR build part 2a (radix path): bucket scatter. bucket = out >> 8.
// tmp[pos] = (out&255)<<24 | k<<19 | in   (requires N<=2^19, K<=32)
// ============================================================================

__global__ void init_bcursor(const int* __restrict__ offsets, int* __restrict__ bcur, int NB, int N) {
    int b = blockIdx.x * 256 + threadIdx.x;
    if (b >= NB) return;
    int row = b << 8; if (row > N) row = N;
    bcur[b * 16] = offsets[row];
}

__global__ void passA(const int* __restrict__ in_idx, const int* __restrict__ out_idx,
                      int* __restrict__ bcur, unsigned* __restrict__ tmp, int M, int NB) {
    __shared__ int cnt[NBMAX];
    __shared__ int gbase[NBMAX];
    for (int t = threadIdx.x; t < NB; t += 256) cnt[t] = 0;
    __syncthreads();
    int k = blockIdx.y;
    int base = blockIdx.x * (256 * TPT);
    unsigned pk[TPT];
    int bk[TPT];
#pragma unroll
    for (int j = 0; j < TPT; ++j) {
        int m = base + threadIdx.x + j * 256;
        if (m < M) {
            size_t e = (size_t)k * M + m;
            unsigned in = (unsigned)in_idx[e];
            unsigned out = (unsigned)out_idx[e];
            pk[j] = ((out & 255u) << 24) | ((unsigned)k << 19) | in;
            bk[j] = (int)(out >> 8);
            atomicAdd(&cnt[bk[j]], 1);
        } else bk[j] = -1;
    }
    __syncthreads();
    for (int b = threadIdx.x; b < NB; b += 256) {
        int c = cnt[b];
        gbase[b] = c ? atomicAdd(&bcur[b * 16], c) : 0;
        cnt[b] = 0;   // reuse as local slot cursor
    }
    __syncthreads();
#pragma unroll
    for (int j = 0; j < TPT; ++j) {
        if (bk[j] >= 0) {
            int slot = atomicAdd(&cnt[bk[j]], 1);
            tmp[gbase[bk[j]] + slot] = pk[j];
        }
    }
}

// Pass B: one block per bucket; counting-sort bucket into LDS, coalesced write.
__global__ void passB(const unsigned* __restrict__ tmp, const int* __restrict__ offsets,
                      unsigned* __restrict__ entries, int N) {
    __shared__ int cur[256];
    __shared__ unsigned stg[CAPB];
    int b = blockIdx.x;
    int r0 = b << 8;
    int rend = r0 + 256; if (rend > N) rend = N;
    int nr = rend - r0;
    int gbeg = offsets[r0];
    int gend = offsets[rend];
    int count = gend - gbeg;
    if (threadIdx.x < nr) cur[threadIdx.x] = offsets[r0 + threadIdx.x] - gbeg;
    __syncthreads();
    if (count <= CAPB) {
        for (int i = threadIdx.x; i < count; i += 256) {
            unsigned v = tmp[gbeg + i];
            int slot = atomicAdd(&cur[v >> 24], 1);
            stg[slot] = v & 0x00FFFFFFu;
        }
        __syncthreads();
        for (int i = threadIdx.x; i < count; i += 256)
            entries[gbeg + i] = stg[i];
    } else {
        for (int i = threadIdx.x; i < count; i += 256) {
            unsigned v = tmp[gbeg + i];
            int slot = atomicAdd(&cur[v >> 24], 1);
            entries[gbeg + slot] = v & 0x00FFFFFFu;
        }
    }
}

// ============================================================================
// CSR build part 2b (fallback): direct atomic scatter
// ============================================================================

__global__ void scatter_entries(const int* __restrict__ in_idx, const int* __restrict__ out_idx,
                                int* __restrict__ cursor, unsigned* __restrict__ entries, int M, int shift) {
    int m = blockIdx.x * blockDim.x + threadIdx.x;
    if (m >= M) return;
    int k = blockIdx.y;
    size_t e = (size_t)k * M + m;
    int pos = atomicAdd(&cursor[out_idx[e]], 1);
    entries[pos] = (unsigned)in_idx[e] | ((unsigned)k << shift);
}

// W2T[k][d][c] = (half)W2[k][c][d]  (27 KB, L1-resident)
__global__ void transpose_W2(const float* __restrict__ W2, __half* __restrict__ W2T, int total) {
    int i = blockIdx.x * 256 + threadIdx.x;
    if (i >= total) return;
    int k = i >> 9;
    int r = i & 511;
    int c = r >> 5, d = r & 31;
    W2T[(k << 9) | (d << 4) | c] = __float2half(W2[i]);
}

// ============================================================================
// Stage 1 gather v2: 16 threads per row. Per 16-entry chunk, lane j loads
// entry j AND its x value (16 independent loads in flight); inner loop is
// shfl + LDS W1 read + fma — no memory in the dependent chain.
// ============================================================================

__global__ void s1_gather_v2(const float* __restrict__ x, const float* __restrict__ W1,
                             const float* __restrict__ g1, const float* __restrict__ b1,
                             const float* __restrict__ m1, const float* __restrict__ v1,
                             const int* __restrict__ offsets, const unsigned* __restrict__ entries,
                             __half* __restrict__ h, int N, int K, int shift, unsigned mask) {
    __shared__ float w1s[32 * 16];
    for (int t = threadIdx.x; t < K * 16; t += 256) w1s[t] = W1[t];
    __syncthreads();
    int row = blockIdx.x * 16 + (threadIdx.x >> 4);
    int c = threadIdx.x & 15;
    if (row >= N) return;
    int beg = offsets[row], end = offsets[row + 1];
    float acc = 0.f;
    for (int base = beg; base < end; base += 16) {
        int cnt = end - base; if (cnt > 16) cnt = 16;
        unsigned ev = entries[base + (c < cnt ? c : cnt - 1)];
        float xv = x[ev & mask];                      // per-lane independent load
        for (int j = 0; j < cnt; ++j) {
            unsigned pk = __shfl(ev, j, 16);
            float xj = __shfl(xv, j, 16);
            acc = fmaf(xj, w1s[(int)((pk >> shift) << 4) | c], acc);
        }
    }
    float scale = g1[c] * rsqrtf(v1[c] + EPSBN);
    float bias = b1[c] - m1[c] * scale;
    h[(size_t)row * 16 + c] = __float2half(elu1(acc * scale + bias));
}

// ============================================================================
// Stage 2 gather v2: one half-wave per row. Per 32-entry chunk: lane j
// cooperatively loads entry j's h-row (32 random lines in flight/half-wave)
// -> LDS staging -> wave waitcnt -> register-accumulated dot loop (no atomics).
// ============================================================================

__global__ void s2_gather_v2(const __half* __restrict__ h, const __half* __restrict__ W2T,
                             const float* __restrict__ g2, const float* __restrict__ b2,
                             const float* __restrict__ m2, const float* __restrict__ v2,
                             const int* __restrict__ offsets, const unsigned* __restrict__ entries,
                             float* __restrict__ out, int N, int shift, unsigned mask) {
    __shared__ __half stg[8][32 * 16 + 8];   // 1KB staging per half-wave (+pad)
    int hw = threadIdx.x >> 5;
    int lane = threadIdx.x & 31;
    int row = blockIdx.x * 8 + hw;
    if (row >= N) return;
    int d = lane;
    int beg = offsets[row], end = offsets[row + 1];
    float acc = 0.f;
    __half* my = stg[hw];
    for (int base = beg; base < end; base += 32) {
        int cnt = end - base; if (cnt > 32) cnt = 32;
        unsigned ev = entries[base + (lane < cnt ? lane : cnt - 1)];
        if (lane < cnt) {
            const float4* hp = (const float4*)(h + ((size_t)(ev & mask) << 4));
            float4 h0 = hp[0], h1 = hp[1];
            float4* dst = (float4*)(my + lane * 16);
            dst[0] = h0;
            dst[1] = h1;
        }
        // wave-lockstep: drain LDS writes before cross-lane reads
        asm volatile("s_waitcnt lgkmcnt(0)" ::: "memory");
        int j = 0;
        for (; j + 1 < cnt; j += 2) {
            unsigned pk0 = __shfl(ev, j, 32);
            unsigned pk1 = __shfl(ev, j + 1, 32);
            const float4* hr0 = (const float4*)(my + j * 16);
            const float4* hr1 = (const float4*)(my + (j + 1) * 16);
            float4 ha0 = hr0[0], hb0 = hr0[1];
            float4 ha1 = hr1[0], hb1 = hr1[1];
            const float4* wp0 = (const float4*)(W2T + (((size_t)(pk0 >> shift) << 9) | ((unsigned)d << 4)));
            const float4* wp1 = (const float4*)(W2T + (((size_t)(pk1 >> shift) << 9) | ((unsigned)d << 4)));
            acc = dot8h(ha0, wp0[0], acc);
            acc = dot8h(hb0, wp0[1], acc);
            acc = dot8h(ha1, wp1[0], acc);
            acc = dot8h(hb1, wp1[1], acc);
        }
        if (j < cnt) {
            unsigned pk0 = __shfl(ev, j, 32);
            const float4* hr0 = (const float4*)(my + j * 16);
            float4 ha0 = hr0[0], hb0 = hr0[1];
            const float4* wp0 = (const float4*)(W2T + (((size_t)(pk0 >> shift) << 9) | ((unsigned)d << 4)));
            acc = dot8h(ha0, wp0[0], acc);
            acc = dot8h(hb0, wp0[1], acc);
        }
        // ensure this chunk's reads done before next chunk overwrites staging
        asm volatile("s_waitcnt lgkmcnt(0)" ::: "memory");
    }
    float scale = g2[d] * rsqrtf(v2[d] + EPSBN);
    float bias = b2[d] - m2[d] * scale;
    out[(size_t)row * 32 + d] = elu1(acc * scale + bias);
}

// ============================================================================
// Last-resort fallback: atomic path (fp32 throughout)
// ============================================================================

__global__ void s1_scatter_slab(const float* __restrict__ x, const int* __restrict__ in_idx,
                                const int* __restrict__ out_idx, float* __restrict__ s, int M, int N) {
    int m = blockIdx.x * blockDim.x + threadIdx.x;
    if (m >= M) return;
    int k = blockIdx.y;
    size_t e = (size_t)k * M + m;
    unsafeAtomicAdd(&s[(size_t)k * N + out_idx[e]], x[in_idx[e]]);
}

__global__ void s1_combine(const float* __restrict__ s, const float* __restrict__ W1,
                           const float* __restrict__ g1, const float* __restrict__ b1,
                           const float* __restrict__ m1, const float* __restrict__ v1,
                           float* __restrict__ h, int N, int K) {
    __shared__ float w[32 * 16];
    __shared__ float sc[16], bi[16];
    for (int t = threadIdx.x; t < K * 16; t += blockDim.x) w[t] = W1[t];
    if (threadIdx.x < 16) {
        float scale = g1[threadIdx.x] * rsqrtf(v1[threadIdx.x] + EPSBN);
        sc[threadIdx.x] = scale;
        bi[threadIdx.x] = b1[threadIdx.x] - m1[threadIdx.x] * scale;
    }
    __syncthreads();
    int n = blockIdx.x * blockDim.x + threadIdx.x;
    if (n >= N) return;
    float acc[16];
#pragma unroll
    for (int c = 0; c < 16; ++c) acc[c] = 0.f;
    for (int k = 0; k < K; ++k) {
        float sv = s[(size_t)k * N + n];
#pragma unroll
        for (int c = 0; c < 16; ++c) acc[c] = fmaf(sv, w[k * 16 + c], acc[c]);
    }
    float4* hv = (float4*)(h + (size_t)n * 16);
#pragma unroll
    for (int q = 0; q < 4; ++q) {
        float4 o;
        o.x = elu1(acc[q * 4 + 0] * sc[q * 4 + 0] + bi[q * 4 + 0]);
        o.y = elu1(acc[q * 4 + 1] * sc[q * 4 + 1] + bi[q * 4 + 1]);
        o.z = elu1(acc[q * 4 + 2] * sc[q * 4 + 2] + bi[q * 4 + 2]);
        o.w = elu1(acc[q * 4 + 3] * sc[q * 4 + 3] + bi[q * 4 + 3]);
        hv[q] = o;
    }
}

__global__ void bn_elu_c(float* __restrict__ buf, const float* __restrict__ g,
                         const float* __restrict__ b, const float* __restrict__ m,
                         const float* __restrict__ v, size_t total, int cmask) {
    size_t i = (size_t)blockIdx.x * blockDim.x + threadIdx.x;
    if (i >= total) return;
    int c = (int)(i & (size_t)cmask);
    float scale = g[c] * rsqrtf(v[c] + EPSBN);
    buf[i] = elu1((buf[i] - m[c]) * scale + b[c]);
}

__global__ void s2_scatter(const float* __restrict__ h, const float* __restrict__ W2,
                           const int* __restrict__ in_idx, const int* __restrict__ out_idx,
                           float* __restrict__ acc, int M) {
    __shared__ float w[16 * 32];
    int k = blockIdx.y;
    for (int t = threadIdx.x; t < 512; t += blockDim.x) w[t] = W2[(size_t)k * 512 + t];
    __syncthreads();
    int m = blockIdx.x * blockDim.x + threadIdx.x;
    if (m >= M) return;
    size_t e = (size_t)k * M + m;
    int in = in_idx[e], out = out_idx[e];
    const float4* hr = (const float4*)(h + (size_t)in * 16);
    float4 h0 = hr[0], h1 = hr[1], h2 = hr[2], h3 = hr[3];
    float hrow[16] = {h0.x, h0.y, h0.z, h0.w, h1.x, h1.y, h1.z, h1.w,
                      h2.x, h2.y, h2.z, h2.w, h3.x, h3.y, h3.z, h3.w};
    float yv[32];
#pragma unroll
    for (int dd = 0; dd < 32; ++dd) yv[dd] = 0.f;
#pragma unroll
    for (int c = 0; c < 16; ++c) {
        float hv = hrow[c];
#pragma unroll
        for (int dd = 0; dd < 32; ++dd) yv[dd] = fmaf(hv, w[c * 32 + dd], yv[dd]);
    }
    float* ar = acc + (size_t)out * 32;
#pragma unroll
    for (int dd = 0; dd < 32; ++dd) unsafeAtomicAdd(&ar[dd], yv[dd]);
}

// ============================================================================

extern "C" void kernel_launch(void* const* d_in, const int* in_sizes, int n_in,
                              void* d_out, int out_size, void* d_ws, size_t ws_size,
                              hipStream_t stream) {
    const float* x  = (const float*)d_in[0];
    const float* W1 = (const float*)d_in[1];
    const float* g1 = (const float*)d_in[2];
    const float* b1 = (const float*)d_in[3];
    const float* m1 = (const float*)d_in[4];
    const float* v1 = (const float*)d_in[5];
    const float* W2 = (const float*)d_in[6];
    const float* g2 = (const float*)d_in[7];
    const float* b2 = (const float*)d_in[8];
    const float* m2 = (const float*)d_in[9];
    const float* v2 = (const float*)d_in[10];
    const int* in_idx  = (const int*)d_in[11];
    const int* out_idx = (const int*)d_in[12];

    const int N  = in_sizes[0];
    const int C1 = in_sizes[2];           // 16
    const int K  = in_sizes[1] / C1;      // 27
    const int M  = in_sizes[11] / K;      // 200000
    const int E  = K * M;                 // 5.4M
    const int nb = (N + 255) / 256;
    const int NB = (N + 255) >> 8;        // radix buckets (256 rows each)

    float* out = (float*)d_out;
    dim3 blk(256);
    dim3 grdKM((M + 255) / 256, K);

    auto align256 = [](size_t v) { return (v + 255) & ~(size_t)255; };
    size_t cntB   = align256((size_t)N * 4);
    size_t offB   = align256((size_t)(N + 1) * 4);
    size_t bsumB  = align256((size_t)nb * 4);
    size_t entB   = align256((size_t)E * 4);
    size_t w2tB   = align256((size_t)K * 512 * 2);
    size_t hB     = align256((size_t)N * 16 * 2);
    size_t baseNeed = cntB + offB + bsumB + entB + w2tB + hB;

    size_t bcurB  = align256((size_t)NB * 16 * 4);
    size_t tmpB   = align256((size_t)E * 4);
    size_t curB   = align256((size_t)N * 4);

    bool canCSR   = (N < (1 << 24)) && (K < 256);
    bool canRadix = (N <= (1 << 19)) && (K <= 32) && (NB <= NBMAX) &&
                    (ws_size >= baseNeed + bcurB + tmpB + curB);

    if (canCSR && ws_size >= baseNeed + curB) {
        char* p = (char*)d_ws;
        int* cnt        = (int*)p;            p += cntB;
        int* offsets    = (int*)p;            p += offB;
        int* bsum       = (int*)p;            p += bsumB;
        unsigned* ent   = (unsigned*)p;       p += entB;
        __half* W2T     = (__half*)p;         p += w2tB;
        __half* h       = (__half*)p;         p += hB;
        int* cursor     = (int*)p;            p += curB;

        const int shift = canRadix ? 19 : 24;
        const unsigned mask = canRadix ? 0x7FFFFu : 0xFFFFFFu;

        hipMemsetAsync(cnt, 0, (size_t)N * 4, stream);
        hist_kernel<<<dim3((M / 4 + 256) / 256, K), blk, 0, stream>>>(out_idx, cnt, M);
        transpose_W2<<<dim3((K * 512 + 255) / 256), blk, 0, stream>>>(W2, W2T, K * 512);
        scan_block_sums<<<dim3(nb), blk, 0, stream>>>(cnt, bsum, N);
        scan_bsums<<<dim3(1), blk, 0, stream>>>(bsum, nb, offsets, N, E);
        scan_final<<<dim3(nb), blk, 0, stream>>>(cnt, bsum, offsets, cursor, N);

        if (canRadix) {
            int* bcur     = (int*)p;          p += bcurB;
            unsigned* tmp = (unsigned*)p;
            init_bcursor<<<dim3((NB + 255) / 256), blk, 0, stream>>>(offsets, bcur, NB, N);
            passA<<<dim3((M + 256 * TPT - 1) / (256 * TPT), K), blk, 0, stream>>>(in_idx, out_idx, bcur, tmp, M, NB);
            passB<<<dim3(NB), blk, 0, stream>>>(tmp, offsets, ent, N);
        } else {
            scatter_entries<<<grdKM, blk, 0, stream>>>(in_idx, out_idx, cursor, ent, M, shift);
        }

        s1_gather_v2<<<dim3((N + 15) / 16), blk, 0, stream>>>(x, W1, g1, b1, m1, v1, offsets, ent, h, N, K, shift, mask);
        s2_gather_v2<<<dim3((N + 7) / 8), blk, 0, stream>>>(h, W2T, g2, b2, m2, v2, offsets, ent, out, N, shift, mask);
        return;
    }

    // ---------------- fallback: atomic path ----------------
    size_t sBytes = align256((size_t)K * N * 4);
    size_t hBytes = (size_t)N * 16 * 4;
    float* hf = (float*)d_ws;
    if (ws_size >= sBytes + hBytes) {
        float* s = (float*)d_ws;
        hf = (float*)((char*)d_ws + sBytes);
        hipMemsetAsync(s, 0, (size_t)K * N * 4, stream);
        s1_scatter_slab<<<grdKM, blk, 0, stream>>>(x, in_idx, out_idx, s, M, N);
        s1_combine<<<dim3((N + 255) / 256), blk, 0, stream>>>(s, W1, g1, b1, m1, v1, hf, N, K);
    }
    hipMemsetAsync(out, 0, (size_t)N * 32 * 4, stream);
    s2_scatter<<<grdKM, blk, 0, stream>>>(hf, W2, in_idx, out_idx, out, M);
    size_t tot2 = (size_t)N * 32;
    bn_elu_c<<<dim3((unsigned)((tot2 + 255) / 256)), blk, 0, stream>>>(out, g2, b2, m2, v2, tot2, 31);
}

// Round 12
// 407.005 us; speedup vs baseline: 6.0036x; 1.5249x over previous
//
#include <hip/hip_runtime.h>
#include <hip/hip_fp16.h>
#include <math.h>

#define EPSBN 1e-5f
#define NBMAX 2048          // max buckets (256 rows each) for radix path
#define TPT 32              // entries per thread in passA/bhist
#define CAPB 8192           // passB2 LDS staging capacity (entries)

typedef int int4v __attribute__((ext_vector_type(4)));

__device__ __forceinline__ float elu1(float x) { return x > 0.f ? x : expm1f(x); }

// dot of 8 half pairs (packed in float4 bit patterns), fp32 accumulate
__device__ __forceinline__ float dot8h(float4 hv, float4 wv, float acc) {
#if defined(__has_builtin)
#if __has_builtin(__builtin_amdgcn_fdot2)
    typedef _Float16 h2v __attribute__((ext_vector_type(2)));
    union { float4 f; h2v h[4]; } a, b;
    a.f = hv; b.f = wv;
#pragma unroll
    for (int i = 0; i < 4; ++i)
        acc = __builtin_amdgcn_fdot2(a.h[i], b.h[i], acc, false);
    return acc;
#endif
#endif
    const __half2* ha = (const __half2*)&hv;
    const __half2* wa = (const __half2*)&wv;
#pragma unroll
    for (int i = 0; i < 4; ++i) {
        float2 hf = __half22float2(ha[i]);
        float2 wf = __half22float2(wa[i]);
        acc = fmaf(hf.x, wf.x, acc);
        acc = fmaf(hf.y, wf.y, acc);
    }
    return acc;
}

// ============================================================================
// Radix path: bucket histogram (LDS) + tiny scan
// ============================================================================

__global__ void bhist_lds(const int* __restrict__ out_idx, int* __restrict__ bcnt, int M, int NB) {
    __shared__ int hcnt[NBMAX];
    for (int t = threadIdx.x; t < NB; t += 256) hcnt[t] = 0;
    __syncthreads();
    int k = blockIdx.y;
    int base = blockIdx.x * (256 * TPT);
#pragma unroll
    for (int j = 0; j < TPT; ++j) {
        int m = base + threadIdx.x + j * 256;
        if (m < M) atomicAdd(&hcnt[out_idx[(size_t)k * M + m] >> 8], 1);
    }
    __syncthreads();
    for (int t = threadIdx.x; t < NB; t += 256) {
        int c = hcnt[t];
        if (c) atomicAdd(&bcnt[t], c);
    }
}

// single block: exclusive scan of bucket counts -> bbase[0..NB]
__global__ void bscan(const int* __restrict__ bcnt, int* __restrict__ bbase, int NB, int E) {
    __shared__ int tmp[256];
    int carry = 0;
    for (int base = 0; base < NB; base += 256) {
        int i = base + threadIdx.x;
        int v = (i < NB) ? bcnt[i] : 0;
        tmp[threadIdx.x] = v;
        __syncthreads();
        for (int off = 1; off < 256; off <<= 1) {
            int t = (threadIdx.x >= off) ? tmp[threadIdx.x - off] : 0;
            __syncthreads();
            tmp[threadIdx.x] += t;
            __syncthreads();
        }
        if (i < NB) bbase[i] = tmp[threadIdx.x] - v + carry;   // exclusive
        carry += tmp[255];
        __syncthreads();
    }
    if (threadIdx.x == 0) bbase[NB] = E;
}

__global__ void init_bcursor2(const int* __restrict__ bbase, int* __restrict__ bcur, int NB) {
    int b = blockIdx.x * 256 + threadIdx.x;
    if (b >= NB) return;
    bcur[b * 16] = bbase[b];
}

// ============================================================================
// passA: bucket scatter. tmp[pos] = (out&255)<<24 | k<<19 | in  (N<=2^19, K<=32)
// ============================================================================

__global__ void passA(const int* __restrict__ in_idx, const int* __restrict__ out_idx,
                      int* __restrict__ bcur, unsigned* __restrict__ tmp, int M, int NB) {
    __shared__ int cnt[NBMAX];
    __shared__ int gbase[NBMAX];
    for (int t = threadIdx.x; t < NB; t += 256) cnt[t] = 0;
    __syncthreads();
    int k = blockIdx.y;
    int base = blockIdx.x * (256 * TPT);
    unsigned pk[TPT];
    int bk[TPT];
#pragma unroll
    for (int j = 0; j < TPT; ++j) {
        int m = base + threadIdx.x + j * 256;
        if (m < M) {
            size_t e = (size_t)k * M + m;
            unsigned in = (unsigned)in_idx[e];
            unsigned out = (unsigned)out_idx[e];
            pk[j] = ((out & 255u) << 24) | ((unsigned)k << 19) | in;
            bk[j] = (int)(out >> 8);
            atomicAdd(&cnt[bk[j]], 1);
        } else bk[j] = -1;
    }
    __syncthreads();
    for (int b = threadIdx.x; b < NB; b += 256) {
        int c = cnt[b];
        gbase[b] = c ? atomicAdd(&bcur[b * 16], c) : 0;
        cnt[b] = 0;   // reuse as local slot cursor
    }
    __syncthreads();
#pragma unroll
    for (int j = 0; j < TPT; ++j) {
        if (bk[j] >= 0) {
            int slot = atomicAdd(&cnt[bk[j]], 1);
            tmp[gbase[bk[j]] + slot] = pk[j];
        }
    }
}

// ============================================================================
// passB2: per bucket — row counting-sort (LDS), write entries + offsets,
// and FUSED stage-1: one thread per row computes h from LDS-resident entries.
// ============================================================================

__global__ void passB2(const unsigned* __restrict__ tmp, const int* __restrict__ bbase,
                       unsigned* __restrict__ entries, int* __restrict__ offsets,
                       const float* __restrict__ x, const float* __restrict__ W1,
                       const float* __restrict__ g1, const float* __restrict__ b1,
                       const float* __restrict__ m1, const float* __restrict__ v1,
                       __half* __restrict__ h, int N, int K, int E, int NB) {
    __shared__ unsigned stg[CAPB];
    __shared__ int rcnt[256], rbase[256], rcur[256], sc[256];
    __shared__ float w1s[32 * 16];
    __shared__ float scb[16], bib[16];
    int b = blockIdx.x;
    int r0 = b << 8;
    int nr = N - r0; if (nr > 256) nr = 256;
    int gbeg = bbase[b], gend = bbase[b + 1];
    int count = gend - gbeg;
    for (int t = threadIdx.x; t < K * 16; t += 256) w1s[t] = W1[t];
    if (threadIdx.x < 16) {
        float scale = g1[threadIdx.x] * rsqrtf(v1[threadIdx.x] + EPSBN);
        scb[threadIdx.x] = scale;
        bib[threadIdx.x] = b1[threadIdx.x] - m1[threadIdx.x] * scale;
    }
    rcnt[threadIdx.x] = 0;
    __syncthreads();
    // row histogram
    for (int i = threadIdx.x; i < count; i += 256)
        atomicAdd(&rcnt[tmp[gbeg + i] >> 24], 1);
    __syncthreads();
    // exclusive scan rcnt -> rbase
    int v = rcnt[threadIdx.x];
    sc[threadIdx.x] = v;
    __syncthreads();
    for (int off = 1; off < 256; off <<= 1) {
        int t = (threadIdx.x >= off) ? sc[threadIdx.x - off] : 0;
        __syncthreads();
        sc[threadIdx.x] += t;
        __syncthreads();
    }
    rbase[threadIdx.x] = sc[threadIdx.x] - v;
    rcur[threadIdx.x] = sc[threadIdx.x] - v;
    if (threadIdx.x < nr) offsets[r0 + threadIdx.x] = gbeg + rbase[threadIdx.x];
    if (b == NB - 1 && threadIdx.x == 0) offsets[N] = E;
    __syncthreads();

    if (count <= CAPB) {
        // sort into LDS staging
        for (int i = threadIdx.x; i < count; i += 256) {
            unsigned vv = tmp[gbeg + i];
            int slot = atomicAdd(&rcur[vv >> 24], 1);
            stg[slot] = vv & 0x00FFFFFFu;
        }
        __syncthreads();
        // coalesced write of row-sorted entries
        for (int i = threadIdx.x; i < count; i += 256)
            entries[gbeg + i] = stg[i];
        // fused stage-1: one thread per row
        if (threadIdx.x < nr) {
            float acc[16];
#pragma unroll
            for (int c = 0; c < 16; ++c) acc[c] = 0.f;
            int rb = rbase[threadIdx.x], re = rb + rcnt[threadIdx.x];
            for (int i = rb; i < re; ++i) {
                unsigned vv = stg[i];
                float xv = x[vv & 0x7FFFFu];
                const float* wr = &w1s[((vv >> 19) & 31) << 4];
#pragma unroll
                for (int c = 0; c < 16; ++c) acc[c] = fmaf(xv, wr[c], acc[c]);
            }
            int row = r0 + threadIdx.x;
            float4 pack[2];
            __half2* hp = (__half2*)pack;
#pragma unroll
            for (int q = 0; q < 8; ++q) {
                __half2 hh;
                hh.x = __float2half(elu1(acc[2 * q] * scb[2 * q] + bib[2 * q]));
                hh.y = __float2half(elu1(acc[2 * q + 1] * scb[2 * q + 1] + bib[2 * q + 1]));
                hp[q] = hh;
            }
            float4* dst = (float4*)(h + (size_t)row * 16);
            dst[0] = pack[0];
            dst[1] = pack[1];
        }
    } else {
        // oversize bucket: unstaged sort directly to global
        for (int i = threadIdx.x; i < count; i += 256) {
            unsigned vv = tmp[gbeg + i];
            int slot = atomicAdd(&rcur[vv >> 24], 1);
            entries[gbeg + slot] = vv & 0x00FFFFFFu;
        }
        __syncthreads();
        if (threadIdx.x < nr) {
            float acc[16];
#pragma unroll
            for (int c = 0; c < 16; ++c) acc[c] = 0.f;
            int rb = rbase[threadIdx.x], re = rb + rcnt[threadIdx.x];
            for (int i = rb; i < re; ++i) {
                unsigned vv = entries[gbeg + i];
                float xv = x[vv & 0x7FFFFu];
                const float* wr = &w1s[((vv >> 19) & 31) << 4];
#pragma unroll
                for (int c = 0; c < 16; ++c) acc[c] = fmaf(xv, wr[c], acc[c]);
            }
            int row = r0 + threadIdx.x;
            float4 pack[2];
            __half2* hp = (__half2*)pack;
#pragma unroll
            for (int q = 0; q < 8; ++q) {
                __half2 hh;
                hh.x = __float2half(elu1(acc[2 * q] * scb[2 * q] + bib[2 * q]));
                hh.y = __float2half(elu1(acc[2 * q + 1] * scb[2 * q + 1] + bib[2 * q + 1]));
                hp[q] = hh;
            }
            float4* dst = (float4*)(h + (size_t)row * 16);
            dst[0] = pack[0];
            dst[1] = pack[1];
        }
    }
}

// W2T[k][d][c] = (half)W2[k][c][d]  (27 KB, L1-resident)
__global__ void transpose_W2(const float* __restrict__ W2, __half* __restrict__ W2T, int total) {
    int i = blockIdx.x * 256 + threadIdx.x;
    if (i >= total) return;
    int k = i >> 9;
    int r = i & 511;
    int c = r >> 5, d = r & 31;
    W2T[(k << 9) | (d << 4) | c] = __float2half(W2[i]);
}

// ============================================================================
// Stage 2 gather v2 (unchanged winner): one half-wave per row; cooperative
// lane-per-entry h staging into LDS; register-accumulated dots.
// ============================================================================

__global__ void s2_gather_v2(const __half* __restrict__ h, const __half* __restrict__ W2T,
                             const float* __restrict__ g2, const float* __restrict__ b2,
                             const float* __restrict__ m2, const float* __restrict__ v2,
                             const int* __restrict__ offsets, const unsigned* __restrict__ entries,
                             float* __restrict__ out, int N, int shift, unsigned mask) {
    __shared__ __half stg[8][32 * 16 + 8];   // 1KB staging per half-wave (+pad)
    int hw = threadIdx.x >> 5;
    int lane = threadIdx.x & 31;
    int row = blockIdx.x * 8 + hw;
    if (row >= N) return;
    int d = lane;
    int beg = offsets[row], end = offsets[row + 1];
    float acc = 0.f;
    __half* my = stg[hw];
    for (int base = beg; base < end; base += 32) {
        int cnt = end - base; if (cnt > 32) cnt = 32;
        unsigned ev = entries[base + (lane < cnt ? lane : cnt - 1)];
        if (lane < cnt) {
            const float4* hp = (const float4*)(h + ((size_t)(ev & mask) << 4));
            float4 h0 = hp[0], h1 = hp[1];
            float4* dst = (float4*)(my + lane * 16);
            dst[0] = h0;
            dst[1] = h1;
        }
        asm volatile("s_waitcnt lgkmcnt(0)" ::: "memory");
        int j = 0;
        for (; j + 1 < cnt; j += 2) {
            unsigned pk0 = __shfl(ev, j, 32);
            unsigned pk1 = __shfl(ev, j + 1, 32);
            const float4* hr0 = (const float4*)(my + j * 16);
            const float4* hr1 = (const float4*)(my + (j + 1) * 16);
            float4 ha0 = hr0[0], hb0 = hr0[1];
            float4 ha1 = hr1[0], hb1 = hr1[1];
            const float4* wp0 = (const float4*)(W2T + (((size_t)(pk0 >> shift) << 9) | ((unsigned)d << 4)));
            const float4* wp1 = (const float4*)(W2T + (((size_t)(pk1 >> shift) << 9) | ((unsigned)d << 4)));
            acc = dot8h(ha0, wp0[0], acc);
            acc = dot8h(hb0, wp0[1], acc);
            acc = dot8h(ha1, wp1[0], acc);
            acc = dot8h(hb1, wp1[1], acc);
        }
        if (j < cnt) {
            unsigned pk0 = __shfl(ev, j, 32);
            const float4* hr0 = (const float4*)(my + j * 16);
            float4 ha0 = hr0[0], hb0 = hr0[1];
            const float4* wp0 = (const float4*)(W2T + (((size_t)(pk0 >> shift) << 9) | ((unsigned)d << 4)));
            acc = dot8h(ha0, wp0[0], acc);
            acc = dot8h(hb0, wp0[1], acc);
        }
        asm volatile("s_waitcnt lgkmcnt(0)" ::: "memory");
    }
    float scale = g2[d] * rsqrtf(v2[d] + EPSBN);
    float bias = b2[d] - m2[d] * scale;
    out[(size_t)row * 32 + d] = elu1(acc * scale + bias);
}

// ============================================================================
// Non-radix CSR fallback kernels (round-11 forms)
// ============================================================================

__global__ void hist_kernel(const int* __restrict__ out_idx, int* __restrict__ cnt, int M) {
    int m = (blockIdx.x * blockDim.x + threadIdx.x) * 4;
    if (m >= M) return;
    size_t e = (size_t)blockIdx.y * M + m;
    if (m + 3 < M) {
        int4v v = *(const int4v*)(out_idx + e);
        atomicAdd(&cnt[v.x], 1);
        atomicAdd(&cnt[v.y], 1);
        atomicAdd(&cnt[v.z], 1);
        atomicAdd(&cnt[v.w], 1);
    } else {
        for (int j = 0; j < M - m; ++j) atomicAdd(&cnt[out_idx[e + j]], 1);
    }
}

__global__ void scan_block_sums(const int* __restrict__ cnt, int* __restrict__ bsum, int N) {
    __shared__ int tmp[256];
    int i = blockIdx.x * 256 + threadIdx.x;
    tmp[threadIdx.x] = (i < N) ? cnt[i] : 0;
    __syncthreads();
    for (int off = 128; off > 0; off >>= 1) {
        if (threadIdx.x < off) tmp[threadIdx.x] += tmp[threadIdx.x + off];
        __syncthreads();
    }
    if (threadIdx.x == 0) bsum[blockIdx.x] = tmp[0];
}

__global__ void scan_bsums(int* __restrict__ bsum, int nb, int* __restrict__ offsets, int N, int E) {
    __shared__ int tmp[256];
    int carry = 0;
    for (int base = 0; base < nb; base += 256) {
        int i = base + threadIdx.x;
        int v = (i < nb) ? bsum[i] : 0;
        tmp[threadIdx.x] = v;
        __syncthreads();
        for (int off = 1; off < 256; off <<= 1) {
            int t = (threadIdx.x >= off) ? tmp[threadIdx.x - off] : 0;
            __syncthreads();
            tmp[threadIdx.x] += t;
            __syncthreads();
        }
        int incl = tmp[threadIdx.x];
        int total = tmp[255];
        if (i < nb) bsum[i] = incl - v + carry;   // exclusive
        carry += total;
        __syncthreads();
    }
    if (threadIdx.x == 0) offsets[N] = E;
}

__global__ void scan_final(const int* __restrict__ cnt, const int* __restrict__ bsum,
                           int* __restrict__ offsets, int* __restrict__ cursor, int N) {
    __shared__ int tmp[256];
    int i = blockIdx.x * 256 + threadIdx.x;
    int v = (i < N) ? cnt[i] : 0;
    tmp[threadIdx.x] = v;
    __syncthreads();
    for (int off = 1; off < 256; off <<= 1) {
        int t = (threadIdx.x >= off) ? tmp[threadIdx.x - off] : 0;
        __syncthreads();
        tmp[threadIdx.x] += t;
        __syncthreads();
    }
    if (i < N) {
        int o = tmp[threadIdx.x] - v + bsum[blockIdx.x];
        offsets[i] = o;
        cursor[i] = o;
    }
}

__global__ void scatter_entries(const int* __restrict__ in_idx, const int* __restrict__ out_idx,
                                int* __restrict__ cursor, unsigned* __restrict__ entries, int M, int shift) {
    int m = blockIdx.x * blockDim.x + threadIdx.x;
    if (m >= M) return;
    int k = blockIdx.y;
    size_t e = (size_t)k * M + m;
    int pos = atomicAdd(&cursor[out_idx[e]], 1);
    entries[pos] = (unsigned)in_idx[e] | ((unsigned)k << shift);
}

__global__ void s1_gather_v2(const float* __restrict__ x, const float* __restrict__ W1,
                             const float* __restrict__ g1, const float* __restrict__ b1,
                             const float* __restrict__ m1, const float* __restrict__ v1,
                             const int* __restrict__ offsets, const unsigned* __restrict__ entries,
                             __half* __restrict__ h, int N, int K, int shift, unsigned mask) {
    __shared__ float w1s[32 * 16];
    for (int t = threadIdx.x; t < K * 16; t += 256) w1s[t] = W1[t];
    __syncthreads();
    int row = blockIdx.x * 16 + (threadIdx.x >> 4);
    int c = threadIdx.x & 15;
    if (row >= N) return;
    int beg = offsets[row], end = offsets[row + 1];
    float acc = 0.f;
    for (int base = beg; base < end; base += 16) {
        int cnt = end - base; if (cnt > 16) cnt = 16;
        unsigned ev = entries[base + (c < cnt ? c : cnt - 1)];
        float xv = x[ev & mask];
        for (int j = 0; j < cnt; ++j) {
            unsigned pk = __shfl(ev, j, 16);
            float xj = __shfl(xv, j, 16);
            acc = fmaf(xj, w1s[(int)((pk >> shift) << 4) | c], acc);
        }
    }
    float scale = g1[c] * rsqrtf(v1[c] + EPSBN);
    float bias = b1[c] - m1[c] * scale;
    h[(size_t)row * 16 + c] = __float2half(elu1(acc * scale + bias));
}

// ============================================================================
// Last-resort fallback: atomic path (fp32 throughout)
// ============================================================================

__global__ void s1_scatter_slab(const float* __restrict__ x, const int* __restrict__ in_idx,
                                const int* __restrict__ out_idx, float* __restrict__ s, int M, int N) {
    int m = blockIdx.x * blockDim.x + threadIdx.x;
    if (m >= M) return;
    int k = blockIdx.y;
    size_t e = (size_t)k * M + m;
    unsafeAtomicAdd(&s[(size_t)k * N + out_idx[e]], x[in_idx[e]]);
}

__global__ void s1_combine(const float* __restrict__ s, const float* __restrict__ W1,
                           const float* __restrict__ g1, const float* __restrict__ b1,
                           const float* __restrict__ m1, const float* __restrict__ v1,
                           float* __restrict__ h, int N, int K) {
    __shared__ float w[32 * 16];
    __shared__ float sc[16], bi[16];
    for (int t = threadIdx.x; t < K * 16; t += blockDim.x) w[t] = W1[t];
    if (threadIdx.x < 16) {
        float scale = g1[threadIdx.x] * rsqrtf(v1[threadIdx.x] + EPSBN);
        sc[threadIdx.x] = scale;
        bi[threadIdx.x] = b1[threadIdx.x] - m1[threadIdx.x] * scale;
    }
    __syncthreads();
    int n = blockIdx.x * blockDim.x + threadIdx.x;
    if (n >= N) return;
    float acc[16];
#pragma unroll
    for (int c = 0; c < 16; ++c) acc[c] = 0.f;
    for (int k = 0; k < K; ++k) {
        float sv = s[(size_t)k * N + n];
#pragma unroll
        for (int c = 0; c < 16; ++c) acc[c] = fmaf(sv, w[k * 16 + c], acc[c]);
    }
    float4* hv = (float4*)(h + (size_t)n * 16);
#pragma unroll
    for (int q = 0; q < 4; ++q) {
        float4 o;
        o.x = elu1(acc[q * 4 + 0] * sc[q * 4 + 0] + bi[q * 4 + 0]);
        o.y = elu1(acc[q * 4 + 1] * sc[q * 4 + 1] + bi[q * 4 + 1]);
        o.z = elu1(acc[q * 4 + 2] * sc[q * 4 + 2] + bi[q * 4 + 2]);
        o.w = elu1(acc[q * 4 + 3] * sc[q * 4 + 3] + bi[q * 4 + 3]);
        hv[q] = o;
    }
}

__global__ void bn_elu_c(float* __restrict__ buf, const float* __restrict__ g,
                         const float* __restrict__ b, const float* __restrict__ m,
                         const float* __restrict__ v, size_t total, int cmask) {
    size_t i = (size_t)blockIdx.x * blockDim.x + threadIdx.x;
    if (i >= total) return;
    int c = (int)(i & (size_t)cmask);
    float scale = g[c] * rsqrtf(v[c] + EPSBN);
    buf[i] = elu1((buf[i] - m[c]) * scale + b[c]);
}

__global__ void s2_scatter(const float* __restrict__ h, const float* __restrict__ W2,
                           const int* __restrict__ in_idx, const int* __restrict__ out_idx,
                           float* __restrict__ acc, int M) {
    __shared__ float w[16 * 32];
    int k = blockIdx.y;
    for (int t = threadIdx.x; t < 512; t += blockDim.x) w[t] = W2[(size_t)k * 512 + t];
    __syncthreads();
    int m = blockIdx.x * blockDim.x + threadIdx.x;
    if (m >= M) return;
    size_t e = (size_t)k * M + m;
    int in = in_idx[e], out = out_idx[e];
    const float4* hr = (const float4*)(h + (size_t)in * 16);
    float4 h0 = hr[0], h1 = hr[1], h2 = hr[2], h3 = hr[3];
    float hrow[16] = {h0.x, h0.y, h0.z, h0.w, h1.x, h1.y, h1.z, h1.w,
                      h2.x, h2.y, h2.z, h2.w, h3.x, h3.y, h3.z, h3.w};
    float yv[32];
#pragma unroll
    for (int dd = 0; dd < 32; ++dd) yv[dd] = 0.f;
#pragma unroll
    for (int c = 0; c < 16; ++c) {
        float hv = hrow[c];
#pragma unroll
        for (int dd = 0; dd < 32; ++dd) yv[dd] = fmaf(hv, w[c * 32 + dd], yv[dd]);
    }
    float* ar = acc + (size_t)out * 32;
#pragma unroll
    for (int dd = 0; dd < 32; ++dd) unsafeAtomicAdd(&ar[dd], yv[dd]);
}

// ============================================================================

extern "C" void kernel_launch(void* const* d_in, const int* in_sizes, int n_in,
                              void* d_out, int out_size, void* d_ws, size_t ws_size,
                              hipStream_t stream) {
    const float* x  = (const float*)d_in[0];
    const float* W1 = (const float*)d_in[1];
    const float* g1 = (const float*)d_in[2];
    const float* b1 = (const float*)d_in[3];
    const float* m1 = (const float*)d_in[4];
    const float* v1 = (const float*)d_in[5];
    const float* W2 = (const float*)d_in[6];
    const float* g2 = (const float*)d_in[7];
    const float* b2 = (const float*)d_in[8];
    const float* m2 = (const float*)d_in[9];
    const float* v2 = (const float*)d_in[10];
    const int* in_idx  = (const int*)d_in[11];
    const int* out_idx = (const int*)d_in[12];

    const int N  = in_sizes[0];
    const int C1 = in_sizes[2];           // 16
    const int K  = in_sizes[1] / C1;      // 27
    const int M  = in_sizes[11] / K;      // 200000
    const int E  = K * M;                 // 5.4M
    const int nb = (N + 255) / 256;
    const int NB = (N + 255) >> 8;        // radix buckets (256 rows each)

    float* out = (float*)d_out;
    dim3 blk(256);
    dim3 grdKM((M + 255) / 256, K);

    auto align256 = [](size_t v) { return (v + 255) & ~(size_t)255; };

    // ---- radix layout ----
    size_t bcntB  = align256((size_t)NB * 4);
    size_t bbaseB = align256((size_t)(NB + 1) * 4);
    size_t bcurB  = align256((size_t)NB * 16 * 4);
    size_t tmpB   = align256((size_t)E * 4);
    size_t entB   = align256((size_t)E * 4);
    size_t offB   = align256((size_t)(N + 1) * 4);
    size_t w2tB   = align256((size_t)K * 512 * 2);
    size_t hB     = align256((size_t)N * 16 * 2);
    size_t radixNeed = bcntB + bbaseB + bcurB + tmpB + entB + offB + w2tB + hB;

    bool canRadix = (N <= (1 << 19)) && (K <= 32) && (NB <= NBMAX) && (ws_size >= radixNeed);

    if (canRadix) {
        char* p = (char*)d_ws;
        int* bcnt       = (int*)p;            p += bcntB;
        int* bbase      = (int*)p;            p += bbaseB;
        int* bcur       = (int*)p;            p += bcurB;
        unsigned* tmp   = (unsigned*)p;       p += tmpB;
        unsigned* ent   = (unsigned*)p;       p += entB;
        int* offsets    = (int*)p;            p += offB;
        __half* W2T     = (__half*)p;         p += w2tB;
        __half* h       = (__half*)p;

        hipMemsetAsync(bcnt, 0, (size_t)NB * 4, stream);
        bhist_lds<<<dim3((M + 256 * TPT - 1) / (256 * TPT), K), blk, 0, stream>>>(out_idx, bcnt, M, NB);
        transpose_W2<<<dim3((K * 512 + 255) / 256), blk, 0, stream>>>(W2, W2T, K * 512);
        bscan<<<dim3(1), blk, 0, stream>>>(bcnt, bbase, NB, E);
        init_bcursor2<<<dim3((NB + 255) / 256), blk, 0, stream>>>(bbase, bcur, NB);
        passA<<<dim3((M + 256 * TPT - 1) / (256 * TPT), K), blk, 0, stream>>>(in_idx, out_idx, bcur, tmp, M, NB);
        passB2<<<dim3(NB), blk, 0, stream>>>(tmp, bbase, ent, offsets, x, W1, g1, b1, m1, v1, h, N, K, E, NB);
        s2_gather_v2<<<dim3((N + 7) / 8), blk, 0, stream>>>(h, W2T, g2, b2, m2, v2, offsets, ent, out, N, 19, 0x7FFFFu);
        return;
    }

    // ---- non-radix CSR layout (round-11 path) ----
    size_t cntB   = align256((size_t)N * 4);
    size_t bsumB  = align256((size_t)nb * 4);
    size_t curB   = align256((size_t)N * 4);
    size_t csrNeed = cntB + offB + bsumB + entB + w2tB + hB + curB;
    bool canCSR = (N < (1 << 24)) && (K < 256) && (ws_size >= csrNeed);

    if (canCSR) {
        char* p = (char*)d_ws;
        int* cnt        = (int*)p;            p += cntB;
        int* offsets    = (int*)p;            p += offB;
        int* bsum       = (int*)p;            p += bsumB;
        unsigned* ent   = (unsigned*)p;       p += entB;
        __half* W2T     = (__half*)p;         p += w2tB;
        __half* h       = (__half*)p;         p += hB;
        int* cursor     = (int*)p;

        hipMemsetAsync(cnt, 0, (size_t)N * 4, stream);
        hist_kernel<<<dim3((M / 4 + 256) / 256, K), blk, 0, stream>>>(out_idx, cnt, M);
        transpose_W2<<<dim3((K * 512 + 255) / 256), blk, 0, stream>>>(W2, W2T, K * 512);
        scan_block_sums<<<dim3(nb), blk, 0, stream>>>(cnt, bsum, N);
        scan_bsums<<<dim3(1), blk, 0, stream>>>(bsum, nb, offsets, N, E);
        scan_final<<<dim3(nb), blk, 0, stream>>>(cnt, bsum, offsets, cursor, N);
        scatter_entries<<<grdKM, blk, 0, stream>>>(in_idx, out_idx, cursor, ent, M, 24);
        s1_gather_v2<<<dim3((N + 15) / 16), blk, 0, stream>>>(x, W1, g1, b1, m1, v1, offsets, ent, h, N, K, 24, 0xFFFFFFu);
        s2_gather_v2<<<dim3((N + 7) / 8), blk, 0, stream>>>(h, W2T, g2, b2, m2, v2, offsets, ent, out, N, 24, 0xFFFFFFu);
        return;
    }

    // ---- last-resort atomic path ----
    size_t sBytes = align256((size_t)K * N * 4);
    size_t hBytes = (size_t)N * 16 * 4;
    float* hf = (float*)d_ws;
    if (ws_size >= sBytes + hBytes) {
        float* s = (float*)d_ws;
        hf = (float*)((char*)d_ws + sBytes);
        hipMemsetAsync(s, 0, (size_t)K * N * 4, stream);
        s1_scatter_slab<<<grdKM, blk, 0, stream>>>(x, in_idx, out_idx, s, M, N);
        s1_combine<<<dim3((N + 255) / 256), blk, 0, stream>>>(s, W1, g1, b1, m1, v1, hf, N, K);
    }
    hipMemsetAsync(out, 0, (size_t)N * 32 * 4, stream);
    s2_scatter<<<grdKM, blk, 0, stream>>>(hf, W2, in_idx, out_idx, out, M);
    size_t tot2 = (size_t)N * 32;
    bn_elu_c<<<dim3((unsigned)((tot2 + 255) / 256)), blk, 0, stream>>>(out, g2, b2, m2, v2, tot2, 31);
}